// Round 2
// baseline (125.581 us; speedup 1.0000x reference)
//
#include <hip/hip_runtime.h>

// QuantumAttention: B=8, S=2048, E=8, H=2, D=4, NQ=8
//
// History: R1 41us, R3 36us, R5 (M=4, 1024 blk, 4 w/SIMD) ~36us attn,
// R6 (M=2, 2048 blk, 8 w/SIMD) NEUTRAL total 87.9 -> attn not latency-bound.
// Pipe model: R6 inner loop = 4096 broadcast ds_read_b128/CU ~= 10-20us of
// per-CU LDS pipe vs ~8.5us VALU -> LDS-pipe-bound. R7: K,V stay in the
// registers of the lanes that computed them (wave w's j-slice == its own
// lanes' j's); inner-loop broadcast via v_readlane -> SGPRs feeding FMAs.
// Zero LDS in the main loop. Predicted attn ~14us, VALU-issue-bound.
//
// NOTE: harness poisons the 256MB workspace with a ~40.5us fill INSIDE the
// timed region (top rocprof dispatch) -- that is the floor; kernel time is
// what we optimize.
//
// Quantum circuit closed-form: c_w = cos(tok[w]+tok[w%4]);
// z[0]=c1..c7, z[q>=1]=c0..cq. Softmax one-pass (scores bounded, fp32 safe);
// 0.5*log2(e) folded into Wq so inner exp is bare v_exp_f32 (exp2).

#define SS 2048
#define EE 8

__device__ __forceinline__ float bcast_lane(float v, int l) {
    return __uint_as_float(__builtin_amdgcn_readlane(__float_as_uint(v), l));
}

// grid 2048: bid = b<<8 | h<<7 | rt<<3 | jw.  256 threads = 4 waves.
// Block: rows rt*128..+127 (2 per lane), j-window jw*256..+255 (64 per wave,
// held in the wave's own lanes' registers).
extern "C" __global__ __launch_bounds__(256, 8)
void qa_attn7(const float* __restrict__ x, const float* __restrict__ Wq,
              const float* __restrict__ Wk, const float* __restrict__ Wv,
              float* __restrict__ wsD, float4* __restrict__ wsA) {
    __shared__ float wrow[96];                    // wq'(scaled), wk, wv
    __shared__ float rden[3 * 128];               // waves 1..3 partials
    __shared__ __align__(16) float4 racc[3 * 128];// 6 KB

    const int bid = blockIdx.x;
    const int jw = bid & 7, rt = (bid >> 3) & 15, h = (bid >> 7) & 1, b = bid >> 8;
    const int tid = threadIdx.x, lane = tid & 63, w = tid >> 6;

    if (tid < 96) {
        const int grp = tid >> 5, d = (tid >> 3) & 3, e = tid & 7;
        const float* W = (grp == 0) ? Wq : (grp == 1 ? Wk : Wv);
        float val = W[(h * 4 + d) * EE + e];
        if (grp == 0) val *= 0.72134752044f;   // 0.5 * log2(e)
        wrow[tid] = val;
    }
    __syncthreads();   // wrow ready

    // ---- this lane's own j: K,V stay in registers ----
    float kk[4], vv[4];
    {
        const int j = jw * 256 + tid;
        const float* xp = x + ((size_t)(b * SS + j)) * EE;
        float xv[8];
        *(float4*)&xv[0] = *(const float4*)xp;
        *(float4*)&xv[4] = *(const float4*)(xp + 4);
        #pragma unroll
        for (int d = 0; d < 4; ++d) {
            float sk = 0.f, sv = 0.f;
            #pragma unroll
            for (int e = 0; e < 8; ++e) {
                sk += xv[e] * wrow[32 + d * 8 + e];
                sv += xv[e] * wrow[64 + d * 8 + e];
            }
            kk[d] = sk; vv[d] = sv;
        }
    }

    // ---- q' (log2-scaled) for this lane's 2 rows ----
    float q[2][4];
    const int row0 = rt * 128 + lane;
    #pragma unroll
    for (int m = 0; m < 2; ++m) {
        const float* xp = x + ((size_t)(b * SS + row0 + m * 64)) * EE;
        float xv[8];
        *(float4*)&xv[0] = *(const float4*)xp;
        *(float4*)&xv[4] = *(const float4*)(xp + 4);
        #pragma unroll
        for (int d = 0; d < 4; ++d) {
            float s = 0.f;
            #pragma unroll
            for (int e = 0; e < 8; ++e) s += xv[e] * wrow[d * 8 + e];
            q[m][d] = s;
        }
    }
    // no barrier needed: main loop consumes only this wave's registers

    // ---- 64-j slice for this wave (its own lanes), 2 rows per lane ----
    float den[2] = {};
    float acc[2][4] = {};
    #pragma unroll
    for (int jl = 0; jl < 64; ++jl) {
        const float k0 = bcast_lane(kk[0], jl), k1 = bcast_lane(kk[1], jl);
        const float k2 = bcast_lane(kk[2], jl), k3 = bcast_lane(kk[3], jl);
        const float v0 = bcast_lane(vv[0], jl), v1 = bcast_lane(vv[1], jl);
        const float v2 = bcast_lane(vv[2], jl), v3 = bcast_lane(vv[3], jl);
        #pragma unroll
        for (int m = 0; m < 2; ++m) {
            const float s = q[m][0] * k0 + q[m][1] * k1
                          + q[m][2] * k2 + q[m][3] * k3;
            const float e = __builtin_amdgcn_exp2f(s);
            den[m] += e;
            acc[m][0] += e * v0; acc[m][1] += e * v1;
            acc[m][2] += e * v2; acc[m][3] += e * v3;
        }
    }

    // ---- single-stage reduce: waves 1..3 park, wave 0 merges + writes ----
    if (w > 0) {
        #pragma unroll
        for (int m = 0; m < 2; ++m) {
            rden[(w - 1) * 128 + lane + m * 64] = den[m];
            racc[(w - 1) * 128 + lane + m * 64] =
                make_float4(acc[m][0], acc[m][1], acc[m][2], acc[m][3]);
        }
    }
    __syncthreads();
    if (w == 0) {
        #pragma unroll
        for (int m = 0; m < 2; ++m) {
            const int r = lane + m * 64;
            float d = den[m] + rden[r] + rden[128 + r] + rden[256 + r];
            float4 a1 = racc[r], a2 = racc[128 + r], a3 = racc[256 + r];
            float4 a = make_float4(acc[m][0] + a1.x + a2.x + a3.x,
                                   acc[m][1] + a1.y + a2.y + a3.y,
                                   acc[m][2] + a1.z + a2.z + a3.z,
                                   acc[m][3] + a1.w + a2.w + a3.w);
            const size_t idx = ((size_t)((b * 2 + h) * 8 + jw)) * SS + row0 + m * 64;
            wsD[idx] = d;
            wsA[idx] = a;
        }
    }
}

// Merge 8 window-partials per (token, head), divide, closed-form quantum, Wo.
// UNCHANGED from R6 (clean A/B on the attn restructure).
extern "C" __global__ __launch_bounds__(64)
void qa_quantum7(const float* __restrict__ wsD, const float4* __restrict__ wsA,
                 const float* __restrict__ Wo, float* __restrict__ out) {
    __shared__ float wo[64];
    const int tid = threadIdx.x;
    wo[tid] = Wo[tid];
    __syncthreads();

    const int g = blockIdx.x * 64 + tid;   // token 0..16383
    const int b = g >> 11, s = g & 2047;

    float tok[8];
    #pragma unroll
    for (int h = 0; h < 2; ++h) {
        float den = 0.f, a0 = 0.f, a1 = 0.f, a2 = 0.f, a3 = 0.f;
        #pragma unroll
        for (int sl = 0; sl < 8; ++sl) {
            const size_t idx = ((size_t)((b * 2 + h) * 8 + sl)) * SS + s;
            den += wsD[idx];
            const float4 p = wsA[idx];
            a0 += p.x; a1 += p.y; a2 += p.z; a3 += p.w;
        }
        const float inv = 1.f / den;
        tok[h * 4 + 0] = a0 * inv; tok[h * 4 + 1] = a1 * inv;
        tok[h * 4 + 2] = a2 * inv; tok[h * 4 + 3] = a3 * inv;
    }

    float c[8];
    #pragma unroll
    for (int ww = 0; ww < 8; ++ww) c[ww] = __cosf(tok[ww] + tok[ww & 3]);

    float z[8];
    float p = 1.f;
    #pragma unroll
    for (int qq = 1; qq < 8; ++qq) { p *= c[qq]; z[qq] = p; }
    z[0] = p;                       // c1..c7
    #pragma unroll
    for (int qq = 1; qq < 8; ++qq) z[qq] *= c[0];   // c0..cq

    float y[8];
    #pragma unroll
    for (int f = 0; f < 8; ++f) {
        float sum = 0.f;
        #pragma unroll
        for (int qq = 0; qq < 8; ++qq) sum += z[qq] * wo[f * 8 + qq];
        y[f] = sum;
    }
    float* op = out + (size_t)g * 8;
    *(float4*)op       = make_float4(y[0], y[1], y[2], y[3]);
    *(float4*)(op + 4) = make_float4(y[4], y[5], y[6], y[7]);
}

extern "C" void kernel_launch(void* const* d_in, const int* in_sizes, int n_in,
                              void* d_out, int out_size, void* d_ws, size_t ws_size,
                              hipStream_t stream) {
    const float* x  = (const float*)d_in[0];
    const float* Wq = (const float*)d_in[1];
    const float* Wk = (const float*)d_in[2];
    const float* Wv = (const float*)d_in[3];
    const float* Wo = (const float*)d_in[4];
    float* out = (float*)d_out;

    float*  wsD = (float*)d_ws;                          // 16*8*2048 floats = 1 MB
    float4* wsA = (float4*)((char*)d_ws + (16 * 8 * 2048) * sizeof(float)); // 4 MB

    qa_attn7<<<dim3(2048), dim3(256), 0, stream>>>(x, Wq, Wk, Wv, wsD, wsA);
    qa_quantum7<<<dim3(256), dim3(64), 0, stream>>>(wsD, wsA, Wo, out);
}

// Round 3
// 100.255 us; speedup vs baseline: 1.2526x; 1.2526x over previous
//
#include <hip/hip_runtime.h>

// QuantumAttention: B=8, S=2048, E=8, H=2, D=4, NQ=8
//
// History: R3/R5/R6 all ~36us attn regardless of M/occupancy -> LDS-broadcast
// pipe bound (wave-uniform ds_read_b128 still returns 64x16B, ~12cyc, shared
// per-CU; ~20us total) + latency stalls. R7 readlane: 63.6us REGRESSION
// (VALU->SGPR->VALU hazard wait-states per readlane).
// R8: K/V broadcast moved to the SCALAR pipe. Prep kernel materializes
// Q'(pre-scaled), K, V to workspace; attn kernel loads K/V at wave-uniform
// addresses -> compiler scalarizes to s_load (separate SMEM pipe, SGPR
// operands feed FMAs directly). Zero LDS, zero barriers, ~20 VGPR, M=1,
// 2048 blocks = 8 waves/SIMD. VALU floor 8.5us; predict attn 10-16us.
// Merge kernel: 2 threads/token (h-split, shfl_xor exchange).
//
// NOTE: harness poisons the 256MB workspace with a ~40.5us fill INSIDE the
// timed region -- fixed floor; kernel time is what we optimize.
//
// Quantum circuit closed-form: c_w = cos(tok[w]+tok[w%4]);
// z[0]=c1..c7, z[q>=1]=c0..cq. Softmax one-pass (scores bounded, fp32 safe);
// 0.5*log2(e) folded into Wq at prep so inner exp is bare v_exp_f32 (exp2).

#define SS 2048
#define EE 8

// ---- prep: Q' (scaled), K, V for all (b,h,s) ----
// qws[(b*2+h)*2048+s] = float4 q'
// kvws[((b*2+h)*2048+j)*2 + {0,1}] = float4 K, float4 V
extern "C" __global__ __launch_bounds__(128)
void qa_prep8(const float* __restrict__ x, const float* __restrict__ Wq,
              const float* __restrict__ Wk, const float* __restrict__ Wv,
              float4* __restrict__ qws, float4* __restrict__ kvws) {
    __shared__ float wrow[192];   // [grp 0..2][(h*4+d)*8+e]; grp0 = Wq*0.5*log2e
    const int tid = threadIdx.x;
    for (int t = tid; t < 192; t += 128) {
        const int grp = t >> 6, r = t & 63;
        const float* W = (grp == 0) ? Wq : (grp == 1 ? Wk : Wv);
        float val = W[r];
        if (grp == 0) val *= 0.72134752044f;   // 0.5 * log2(e)
        wrow[t] = val;
    }
    __syncthreads();

    const int g = blockIdx.x * 128 + tid;   // token 0..16383
    const int b = g >> 11, s = g & 2047;
    const float* xp = x + (size_t)g * EE;
    float xv[8];
    *(float4*)&xv[0] = *(const float4*)xp;
    *(float4*)&xv[4] = *(const float4*)(xp + 4);

    #pragma unroll
    for (int h = 0; h < 2; ++h) {
        float qd[4], kd[4], vd[4];
        #pragma unroll
        for (int d = 0; d < 4; ++d) {
            const int r = (h * 4 + d) * 8;
            float sq = 0.f, sk = 0.f, sv = 0.f;
            #pragma unroll
            for (int e = 0; e < 8; ++e) {
                sq += xv[e] * wrow[r + e];
                sk += xv[e] * wrow[64 + r + e];
                sv += xv[e] * wrow[128 + r + e];
            }
            qd[d] = sq; kd[d] = sk; vd[d] = sv;
        }
        const size_t o = (size_t)(b * 2 + h) * SS + s;
        qws[o] = make_float4(qd[0], qd[1], qd[2], qd[3]);
        kvws[o * 2]     = make_float4(kd[0], kd[1], kd[2], kd[3]);
        kvws[o * 2 + 1] = make_float4(vd[0], vd[1], vd[2], vd[3]);
    }
}

// ---- attn: grid 2048 = bh(16) x rt(8) x jw(16); 256 threads, 1 row/thread.
// K/V loads are wave-uniform -> scalar pipe; zero LDS; zero barriers.
extern "C" __global__ __launch_bounds__(256, 8)
void qa_attn8(const float4* __restrict__ qws, const float4* __restrict__ kvws,
              float* __restrict__ wsD, float4* __restrict__ wsA) {
    const int bid = blockIdx.x;
    const int jw = bid & 15, rt = (bid >> 4) & 7, bh = bid >> 7;
    const int tid = threadIdx.x;
    const int row = rt * 256 + tid;

    const float4 q = qws[(size_t)bh * SS + row];
    const float4* kvp = kvws + ((size_t)bh * SS + jw * 128) * 2;

    float den = 0.f, a0 = 0.f, a1 = 0.f, a2 = 0.f, a3 = 0.f;
    #pragma unroll 4
    for (int jl = 0; jl < 128; ++jl) {
        const float4 k4 = kvp[jl * 2];       // wave-uniform -> s_load
        const float4 v4 = kvp[jl * 2 + 1];
        const float sc = q.x * k4.x + q.y * k4.y + q.z * k4.z + q.w * k4.w;
        const float e = __builtin_amdgcn_exp2f(sc);
        den += e;
        a0 += e * v4.x; a1 += e * v4.y; a2 += e * v4.z; a3 += e * v4.w;
    }
    const size_t idx = ((size_t)(bh * 16 + jw)) * SS + row;
    wsD[idx] = den;
    wsA[idx] = make_float4(a0, a1, a2, a3);
}

// ---- merge + quantum: 2 threads per token (one per head), shfl exchange ----
extern "C" __global__ __launch_bounds__(128)
void qa_merge8(const float* __restrict__ wsD, const float4* __restrict__ wsA,
               const float* __restrict__ Wo, float* __restrict__ out) {
    __shared__ float wo[64];
    const int tid = threadIdx.x;
    if (tid < 64) wo[tid] = Wo[tid];
    __syncthreads();

    const int gt = blockIdx.x * 128 + tid;   // 0..32767
    const int g = gt >> 1, h = gt & 1;       // token, head
    const int b = g >> 11, s = g & 2047;

    float den = 0.f, a0 = 0.f, a1 = 0.f, a2 = 0.f, a3 = 0.f;
    #pragma unroll
    for (int sl = 0; sl < 16; ++sl) {
        const size_t idx = ((size_t)((b * 2 + h) * 16 + sl)) * SS + s;
        den += wsD[idx];
        const float4 p = wsA[idx];
        a0 += p.x; a1 += p.y; a2 += p.z; a3 += p.w;
    }
    const float inv = 1.f / den;
    float own[4] = {a0 * inv, a1 * inv, a2 * inv, a3 * inv};
    float oth[4];
    #pragma unroll
    for (int c = 0; c < 4; ++c) oth[c] = __shfl_xor(own[c], 1);

    float tok[8];
    #pragma unroll
    for (int c = 0; c < 4; ++c) {
        tok[c]     = h ? oth[c] : own[c];
        tok[4 + c] = h ? own[c] : oth[c];
    }

    float cc[8];
    #pragma unroll
    for (int ww = 0; ww < 8; ++ww) cc[ww] = __cosf(tok[ww] + tok[ww & 3]);

    float z[8];
    float p = 1.f;
    #pragma unroll
    for (int qq = 1; qq < 8; ++qq) { p *= cc[qq]; z[qq] = p; }
    z[0] = p;                       // c1..c7
    #pragma unroll
    for (int qq = 1; qq < 8; ++qq) z[qq] *= cc[0];   // c0..cq

    // this thread writes outputs f = h*4 .. h*4+3
    float y[4];
    #pragma unroll
    for (int f = 0; f < 4; ++f) {
        float sum = 0.f;
        #pragma unroll
        for (int qq = 0; qq < 8; ++qq) sum += z[qq] * wo[(h * 4 + f) * 8 + qq];
        y[f] = sum;
    }
    float4* op = (float4*)(out + (size_t)g * 8) + h;
    *op = make_float4(y[0], y[1], y[2], y[3]);
}

extern "C" void kernel_launch(void* const* d_in, const int* in_sizes, int n_in,
                              void* d_out, int out_size, void* d_ws, size_t ws_size,
                              hipStream_t stream) {
    const float* x  = (const float*)d_in[0];
    const float* Wq = (const float*)d_in[1];
    const float* Wk = (const float*)d_in[2];
    const float* Wv = (const float*)d_in[3];
    const float* Wo = (const float*)d_in[4];
    float* out = (float*)d_out;

    // workspace layout (all 16B-aligned):
    // [kvws 1MB][qws 512KB][wsD 2MB][wsA 8MB]
    float4* kvws = (float4*)d_ws;
    float4* qws  = (float4*)((char*)d_ws + (1u << 20));
    float*  wsD  = (float*)((char*)d_ws + (1u << 20) + (512u << 10));
    float4* wsA  = (float4*)((char*)d_ws + (1u << 20) + (512u << 10) + (2u << 20));

    qa_prep8<<<dim3(128), dim3(128), 0, stream>>>(x, Wq, Wk, Wv, qws, kvws);
    qa_attn8<<<dim3(2048), dim3(256), 0, stream>>>(qws, kvws, wsD, wsA);
    qa_merge8<<<dim3(256), dim3(128), 0, stream>>>(wsD, wsA, Wo, out);
}

// Round 4
// 86.616 us; speedup vs baseline: 1.4498x; 1.1575x over previous
//
#include <hip/hip_runtime.h>

// QuantumAttention: B=8, S=2048, E=8, H=2, D=4, NQ=8
//
// History: R5 87us (attn ~36 @4w/SIMD + quantum 64x256 ~10). R6 87.9 NEUTRAL
// but confounded: attn6 (M=2, 8 blk/CU) improved 36->~26, while quantum
// regridded to 256x64 = 1 wave/CU regressed 10->~21 (measured via R7:
// 125.58 - 40.5 fill - 63.6 attn7 = 21.5). R7 readlane: VALU->SGPR hazard
// regression. R8 scalar-pipe: 3 confounded kernels, absmax doubled; reverted.
// R9: attn6 kept BIT-IDENTICAL; merge rebuilt: 2 threads/token (h-split,
// shfl_xor exchange), 128 blocks x 256 thr = 4 waves/block, 8 slice loads
// unrolled/batched per thread. Predict merge ~21 -> ~3-4us, total ~73us.
//
// NOTE: harness poisons the 256MB workspace with a ~40.5-41.8us fill INSIDE
// the timed region (top rocprof dispatches) -- fixed floor; our kernels sit
// below it so attribute via total dur_us deltas, one change per round.
//
// Quantum circuit closed-form: c_w = cos(tok[w]+tok[w%4]);
// z[0]=c1..c7, z[q>=1]=c0..cq. Softmax one-pass (scores bounded, fp32 safe);
// 0.5*log2(e) folded into Wq so inner exp is bare v_exp_f32 (exp2).

#define SS 2048
#define EE 8

// grid 2048: bid = b<<8 | h<<7 | rt<<3 | jw.  256 threads = 4 waves.
// Block: rows rt*128..+127 (2 per lane), j-window jw*256..+255 (64 per wave).
extern "C" __global__ __launch_bounds__(256, 8)
void qa_attn9(const float* __restrict__ x, const float* __restrict__ Wq,
              const float* __restrict__ Wk, const float* __restrict__ Wv,
              float* __restrict__ wsD, float4* __restrict__ wsA) {
    __shared__ float wrow[96];                    // wq'(scaled), wk, wv
    __shared__ __align__(16) float4 kv4[512];     // 256 j x {K4,V4} = 8 KB
    __shared__ float rden[3 * 128];               // waves 1..3 partials
    __shared__ __align__(16) float4 racc[3 * 128];// 6 KB

    const int bid = blockIdx.x;
    const int jw = bid & 7, rt = (bid >> 3) & 15, h = (bid >> 7) & 1, b = bid >> 8;
    const int tid = threadIdx.x, lane = tid & 63, w = tid >> 6;

    if (tid < 96) {
        const int grp = tid >> 5, d = (tid >> 3) & 3, e = tid & 7;
        const float* W = (grp == 0) ? Wq : (grp == 1 ? Wk : Wv);
        float val = W[(h * 4 + d) * EE + e];
        if (grp == 0) val *= 0.72134752044f;   // 0.5 * log2(e)
        wrow[tid] = val;
    }
    __syncthreads();   // wrow ready

    // ---- stage K,V for the 256-j window (one j per thread) ----
    {
        const int j = jw * 256 + tid;
        const float* xp = x + ((size_t)(b * SS + j)) * EE;
        float xv[8];
        *(float4*)&xv[0] = *(const float4*)xp;
        *(float4*)&xv[4] = *(const float4*)(xp + 4);
        float kk[4], vv[4];
        #pragma unroll
        for (int d = 0; d < 4; ++d) {
            float sk = 0.f, sv = 0.f;
            #pragma unroll
            for (int e = 0; e < 8; ++e) {
                sk += xv[e] * wrow[32 + d * 8 + e];
                sv += xv[e] * wrow[64 + d * 8 + e];
            }
            kk[d] = sk; vv[d] = sv;
        }
        kv4[tid * 2]     = make_float4(kk[0], kk[1], kk[2], kk[3]);
        kv4[tid * 2 + 1] = make_float4(vv[0], vv[1], vv[2], vv[3]);
    }

    // ---- q' (log2-scaled) for this lane's 2 rows ----
    float q[2][4];
    const int row0 = rt * 128 + lane;
    #pragma unroll
    for (int m = 0; m < 2; ++m) {
        const float* xp = x + ((size_t)(b * SS + row0 + m * 64)) * EE;
        float xv[8];
        *(float4*)&xv[0] = *(const float4*)xp;
        *(float4*)&xv[4] = *(const float4*)(xp + 4);
        #pragma unroll
        for (int d = 0; d < 4; ++d) {
            float s = 0.f;
            #pragma unroll
            for (int e = 0; e < 8; ++e) s += xv[e] * wrow[d * 8 + e];
            q[m][d] = s;
        }
    }
    __syncthreads();   // kv4 ready

    // ---- 64-j slice for this wave, 2 rows per lane ----
    float den[2] = {};
    float acc[2][4] = {};
    const float4* kvp = &kv4[w * 128];
    #pragma unroll 2
    for (int jl = 0; jl < 64; ++jl) {
        const float4 kk = kvp[jl * 2];      // wave-broadcast
        const float4 vv = kvp[jl * 2 + 1];
        #pragma unroll
        for (int m = 0; m < 2; ++m) {
            const float s = q[m][0] * kk.x + q[m][1] * kk.y
                          + q[m][2] * kk.z + q[m][3] * kk.w;
            const float e = __builtin_amdgcn_exp2f(s);
            den[m] += e;
            acc[m][0] += e * vv.x; acc[m][1] += e * vv.y;
            acc[m][2] += e * vv.z; acc[m][3] += e * vv.w;
        }
    }

    // ---- single-stage reduce: waves 1..3 park, wave 0 merges + writes ----
    if (w > 0) {
        #pragma unroll
        for (int m = 0; m < 2; ++m) {
            rden[(w - 1) * 128 + lane + m * 64] = den[m];
            racc[(w - 1) * 128 + lane + m * 64] =
                make_float4(acc[m][0], acc[m][1], acc[m][2], acc[m][3]);
        }
    }
    __syncthreads();
    if (w == 0) {
        #pragma unroll
        for (int m = 0; m < 2; ++m) {
            const int r = lane + m * 64;
            float d = den[m] + rden[r] + rden[128 + r] + rden[256 + r];
            float4 a1 = racc[r], a2 = racc[128 + r], a3 = racc[256 + r];
            float4 a = make_float4(acc[m][0] + a1.x + a2.x + a3.x,
                                   acc[m][1] + a1.y + a2.y + a3.y,
                                   acc[m][2] + a1.z + a2.z + a3.z,
                                   acc[m][3] + a1.w + a2.w + a3.w);
            const size_t idx = ((size_t)((b * 2 + h) * 8 + jw)) * SS + row0 + m * 64;
            wsD[idx] = d;
            wsA[idx] = a;
        }
    }
}

// ---- merge + quantum: 2 threads/token (one per head), shfl_xor exchange.
// 128 blocks x 256 threads = 4 waves/block on 128 CUs; 16 batched loads
// per thread -> latency hidden (was 1 wave/CU, ~21us; predict ~3-4us).
extern "C" __global__ __launch_bounds__(256)
void qa_merge9(const float* __restrict__ wsD, const float4* __restrict__ wsA,
               const float* __restrict__ Wo, float* __restrict__ out) {
    __shared__ float wo[64];
    const int tid = threadIdx.x;
    if (tid < 64) wo[tid] = Wo[tid];
    __syncthreads();

    const int gt = blockIdx.x * 256 + tid;   // 0..32767
    const int g = gt >> 1, h = gt & 1;       // token, head
    const int b = g >> 11, s = g & 2047;

    float den = 0.f, a0 = 0.f, a1 = 0.f, a2 = 0.f, a3 = 0.f;
    #pragma unroll
    for (int sl = 0; sl < 8; ++sl) {
        const size_t idx = ((size_t)((b * 2 + h) * 8 + sl)) * SS + s;
        den += wsD[idx];
        const float4 p = wsA[idx];
        a0 += p.x; a1 += p.y; a2 += p.z; a3 += p.w;
    }
    const float inv = 1.f / den;
    float own[4] = {a0 * inv, a1 * inv, a2 * inv, a3 * inv};
    float oth[4];
    #pragma unroll
    for (int c = 0; c < 4; ++c) oth[c] = __shfl_xor(own[c], 1);

    float tok[8];
    #pragma unroll
    for (int c = 0; c < 4; ++c) {
        tok[c]     = h ? oth[c] : own[c];
        tok[4 + c] = h ? own[c] : oth[c];
    }

    float cc[8];
    #pragma unroll
    for (int ww = 0; ww < 8; ++ww) cc[ww] = __cosf(tok[ww] + tok[ww & 3]);

    float z[8];
    float p = 1.f;
    #pragma unroll
    for (int qq = 1; qq < 8; ++qq) { p *= cc[qq]; z[qq] = p; }
    z[0] = p;                       // c1..c7
    #pragma unroll
    for (int qq = 1; qq < 8; ++qq) z[qq] *= cc[0];   // c0..cq

    // this thread writes outputs f = h*4 .. h*4+3
    float y[4];
    #pragma unroll
    for (int f = 0; f < 4; ++f) {
        float sum = 0.f;
        #pragma unroll
        for (int qq = 0; qq < 8; ++qq) sum += z[qq] * wo[(h * 4 + f) * 8 + qq];
        y[f] = sum;
    }
    float4* op = (float4*)(out + (size_t)g * 8) + h;
    *op = make_float4(y[0], y[1], y[2], y[3]);
}

extern "C" void kernel_launch(void* const* d_in, const int* in_sizes, int n_in,
                              void* d_out, int out_size, void* d_ws, size_t ws_size,
                              hipStream_t stream) {
    const float* x  = (const float*)d_in[0];
    const float* Wq = (const float*)d_in[1];
    const float* Wk = (const float*)d_in[2];
    const float* Wv = (const float*)d_in[3];
    const float* Wo = (const float*)d_in[4];
    float* out = (float*)d_out;

    float*  wsD = (float*)d_ws;                          // 16*8*2048 floats = 1 MB
    float4* wsA = (float4*)((char*)d_ws + (16 * 8 * 2048) * sizeof(float)); // 4 MB

    qa_attn9<<<dim3(2048), dim3(256), 0, stream>>>(x, Wq, Wk, Wv, wsD, wsA);
    qa_merge9<<<dim3(128), dim3(256), 0, stream>>>(wsD, wsA, Wo, out);
}